// Round 12
// baseline (1023.667 us; speedup 1.0000x reference)
//
#include <hip/hip_runtime.h>
#include <cstddef>

// NLM: h=7/255, template 7x7 (TH=3), search 21x21 (SH=10), reflect padding.
// R13 = R9 per-lane code on a 32x64 TILE, 512 threads (8 waves):
//   Bv = 6 row-groups x 38 cols = 228 lanes (waves 0-3), per-lane work
//   byte-identical to R9 (17 reads, 17 d^2, 11-row sliding sum, 11 writes).
//   C = 256 lanes (waves 4-7), py 0..63, per-lane code identical to R9.
//   Same 441 rounds / 2-buffer / 1-barrier-per-offset scheme.
// WHY: R9+R12 proved the kernel is NOT VALU-issue-bound (R12 cut issued
//   VALU 30% -> time WORSE; VALUBusy 73.7->45.7). The wall is the per-round
//   fixed cost (~50%: barrier drain + post-barrier ds latency + convoy).
//   Doubling work per round halves total block-rounds (2048 blocks x 441)
//   -> fixed overhead amortized 2x. Bonus: halo traffic/px 3.5 -> 2.7 floats.
// Rows 64,65 of vsh are junk (group 5 covers 55..65; outputs end at 63) --
//   written, never read; their xs reads are in-bounds (XROWS=92 covers them).
// R9 exact exp-block skip kept (exp2 underflow -> +0.0 for h > 3.84).
// Lessons: no ox-loop unrolling (R2); scalar Bv per lane (R5/R6); float vsh
// (R7); no deeper LDS ring (R8); no parity swap (R10); no reg prefetch
// (R11); no offset-pair packing (R12 - not VALU-bound).

constexpr int TSX   = 32;
constexpr int TSY   = 64;
constexpr int XSTR  = 61;            // odd -> benign bank aliasing
constexpr int XROWS = 92;            // image rows gy0-13 .. gy0+78
constexpr int XSZ   = XROWS * XSTR;  // 5612
constexpr int VSTR  = 42;            // even (float2-aligned), 42%8!=0
constexpr int VROWS = 66;            // 64 real + 2 junk (group-5 tail)
constexpr int VS_SZ = VROWS * VSTR;  // 2772 per buffer

__device__ __forceinline__ int refl(int i, int n) {
    i = (i < 0) ? -i : i;
    return (i >= n) ? (2 * n - 2 - i) : i;
}

template<bool FAST>
__device__ __forceinline__ void nlm_body(const float* __restrict__ img,
                                         float* __restrict__ out,
                                         int H, int W, int gx0, int gy0,
                                         float* __restrict__ xs,
                                         float* __restrict__ vsh, int tid)
{
    // ---- load xs (clip to [0,1], reflect indexing) ----
    for (int e = tid; e < XSZ; e += 512) {
        int i = e / XSTR, j = e - i * XSTR;
        int jj = (j > 57) ? 57 : j;  // cols 58..60: stride pad (never read)
        int gy = refl(gy0 - 13 + i, H);
        int gx = refl(gx0 - 13 + jj, W);
        float v = img[(size_t)gy * W + gx];
        xs[e] = fminf(fmaxf(v, 0.0f), 1.0f);
    }
    __syncthreads();

    // ---- Bv setup: 228 lanes = 38 cols x 6 row-groups (11 rows, 17 q's) ----
    const bool bv = (tid < 228);
    float u[17];
    int   aB = 0;                    // FAST: single address, +i*XSTR rows
    int   aS[17];                    // EDGE: per-row reflected addresses
    int   wb = 0;
    {
        int t  = bv ? tid : 0;
        int g  = t / 38;             // 0..5
        int cc = t - g * 38;
        int r  = g * 11;             // rows r..r+10 (64,65 junk for g=5)
        int mxm10 = refl(gx0 + cc - 3, W) - gx0 + 3;
        if constexpr (FAST) {
            aB = r * XSTR + mxm10;
#pragma unroll
            for (int i = 0; i < 17; ++i)
                u[i] = xs[(r + i + 10) * XSTR + mxm10 + 10];
        } else {
#pragma unroll
            for (int i = 0; i < 17; ++i) {
                int my = refl(gy0 + r + i - 3, H) - gy0 + 13;
                u[i]  = xs[my * XSTR + mxm10 + 10];
                aS[i] = (my - 10) * XSTR + mxm10;
            }
        }
        wb = r * VSTR + cc;
    }

    // ---- C setup: 256 lanes = 64 rows x 4 groups of 8 cols ----
    const bool cact = (tid >= 256);
    const int ct = cact ? (tid - 256) : 0;
    const int py = ct >> 2;                     // 0..63
    const int c8 = (ct & 3) * 8;
    const int vb = py * VSTR + c8;              // float2-aligned (even)
    int svC = (py + 3) * XSTR + (c8 + 3);       // row base, advances per oy

    int oxB = 0;                                 // uniform ox state machines
    int oxC = 0;

    float ws[8], ac[8];
#pragma unroll
    for (int k = 0; k < 8; ++k) { ws[k] = 0.f; ac[k] = 0.f; }
    // w = exp(-mean49(d)/H2) = exp2(K * sum49(d))
    const float K = -(65025.0f / 2401.0f) * 1.4426950408889634f;  // ~ -39.07
    const float HSKIP = 3.95f;  // h > 3.95 => h*K <= -154 => exp2 == +0.0f

    auto bv_step = [&](int buf) {
        if (bv) {
            float* vo = vsh + buf * VS_SZ + wb;
            float q[17];
            if constexpr (FAST) {
#pragma unroll
                for (int i = 0; i < 17; ++i)
                    q[i] = xs[aB + i * XSTR];
            } else {
#pragma unroll
                for (int i = 0; i < 17; ++i)
                    q[i] = xs[aS[i]];
            }
#pragma unroll
            for (int i = 0; i < 17; ++i) {
                float d = u[i] - q[i];
                q[i] = d * d;
            }
            float s[11];
            s[0] = ((q[0] + q[1]) + (q[2] + q[3])) + ((q[4] + q[5]) + q[6]);
#pragma unroll
            for (int k = 1; k < 11; ++k)
                s[k] = s[k - 1] + (q[k + 6] - q[k - 1]);
#pragma unroll
            for (int k = 0; k < 11; ++k)
                vo[k * VSTR] = s[k];   // rows 64,65 = junk, never read
            if constexpr (FAST) {
                aB += (oxB == 20) ? (XSTR - 20) : 1;
            } else {
                int step = (oxB == 20) ? (XSTR - 20) : 1;
#pragma unroll
                for (int i = 0; i < 17; ++i) aS[i] += step;
            }
        }
        oxB = (oxB == 20) ? 0 : (oxB + 1);
    };

    auto c_step = [&](int buf) {
        if (cact) {
            const float2* vp =
                reinterpret_cast<const float2*>(vsh + buf * VS_SZ + vb);
            float2 tA = vp[0], tB = vp[1], tC = vp[2], tD = vp[3];
            float2 tE = vp[4], tF = vp[5], tG = vp[6];
            float h0 = ((tA.x + tA.y) + (tB.x + tB.y)) + ((tC.x + tC.y) + tD.x);
            float h1 = h0 - tA.x + tD.y;
            float h2 = h1 - tA.y + tE.x;
            float h3 = h2 - tB.x + tE.y;
            float h4 = h3 - tB.y + tF.x;
            float h5 = h4 - tC.x + tF.y;
            float h6 = h5 - tC.y + tG.x;
            float h7 = h6 - tD.x + tG.y;
            float m = fminf(fminf(fminf(h0, h1), fminf(h2, h3)),
                            fminf(fminf(h4, h5), fminf(h6, h7)));
            if (__builtin_expect(__ballot(m <= HSKIP) != 0ull, 0)) {
                const int sp = svC + oxC;
                float x0 = xs[sp],     x1 = xs[sp + 1];
                float x2 = xs[sp + 2], x3 = xs[sp + 3];
                float x4 = xs[sp + 4], x5 = xs[sp + 5];
                float x6 = xs[sp + 6], x7 = xs[sp + 7];
                float w;
                w = __builtin_amdgcn_exp2f(h0 * K); ws[0] += w; ac[0] = fmaf(w, x0, ac[0]);
                w = __builtin_amdgcn_exp2f(h1 * K); ws[1] += w; ac[1] = fmaf(w, x1, ac[1]);
                w = __builtin_amdgcn_exp2f(h2 * K); ws[2] += w; ac[2] = fmaf(w, x2, ac[2]);
                w = __builtin_amdgcn_exp2f(h3 * K); ws[3] += w; ac[3] = fmaf(w, x3, ac[3]);
                w = __builtin_amdgcn_exp2f(h4 * K); ws[4] += w; ac[4] = fmaf(w, x4, ac[4]);
                w = __builtin_amdgcn_exp2f(h5 * K); ws[5] += w; ac[5] = fmaf(w, x5, ac[5]);
                w = __builtin_amdgcn_exp2f(h6 * K); ws[6] += w; ac[6] = fmaf(w, x6, ac[6]);
                w = __builtin_amdgcn_exp2f(h7 * K); ws[7] += w; ac[7] = fmaf(w, x7, ac[7]);
            }
            // else: all 8 weights are exactly +0.0f for every lane -> no-op.
        }
        if (oxC == 20) { oxC = 0; svC += XSTR; } else { ++oxC; }
    };

    // ---- pipelined offset loop: Bv(i) || C(i-1), 1 barrier/iter ----
    bv_step(0);
    __syncthreads();
#pragma unroll 1
    for (int i = 1; i < 441; ++i) {
        bv_step(i & 1);
        c_step(1 - (i & 1));
        __syncthreads();
        // barrier fences: C's reads of buf (i-1)&1 from next iter's Bv writes
        // to that buffer, and Bv's writes of buf i&1 from next iter's C reads.
    }
    c_step(0);   // offset 440 lives in buffer 0

    if (cact) {
        float4 oA, oB;
        oA.x = fminf(fmaxf(ac[0] * __builtin_amdgcn_rcpf(ws[0]), 0.f), 1.f);
        oA.y = fminf(fmaxf(ac[1] * __builtin_amdgcn_rcpf(ws[1]), 0.f), 1.f);
        oA.z = fminf(fmaxf(ac[2] * __builtin_amdgcn_rcpf(ws[2]), 0.f), 1.f);
        oA.w = fminf(fmaxf(ac[3] * __builtin_amdgcn_rcpf(ws[3]), 0.f), 1.f);
        oB.x = fminf(fmaxf(ac[4] * __builtin_amdgcn_rcpf(ws[4]), 0.f), 1.f);
        oB.y = fminf(fmaxf(ac[5] * __builtin_amdgcn_rcpf(ws[5]), 0.f), 1.f);
        oB.z = fminf(fmaxf(ac[6] * __builtin_amdgcn_rcpf(ws[6]), 0.f), 1.f);
        oB.w = fminf(fmaxf(ac[7] * __builtin_amdgcn_rcpf(ws[7]), 0.f), 1.f);
        float* op = &out[((size_t)blockIdx.z * H + (gy0 + py)) * W + (gx0 + c8)];
        *reinterpret_cast<float4*>(op)     = oA;
        *reinterpret_cast<float4*>(op + 4) = oB;
    }
}

__global__ __launch_bounds__(512)
void nlm_kernel(const float* __restrict__ img_all, float* __restrict__ out,
                int H, int W) {
    __shared__ __align__(16) float xs[XSZ];
    __shared__ __align__(16) float vsh[2 * VS_SZ];
    const int tid = threadIdx.x;
    const int gx0 = blockIdx.x * TSX;
    const int gy0 = blockIdx.y * TSY;
    const float* img = img_all + (size_t)blockIdx.z * H * W;
    // FAST iff no REAL patch-center row (gy0-3 .. gy0+66) folds at a y-edge.
    // (Junk rows 64,65 read in-bounds xs either way; values discarded.)
    if (gy0 - 3 >= 0 && gy0 + 66 < H)
        nlm_body<true>(img, out, H, W, gx0, gy0, xs, vsh, tid);
    else
        nlm_body<false>(img, out, H, W, gx0, gy0, xs, vsh, tid);
}

extern "C" void kernel_launch(void* const* d_in, const int* in_sizes, int n_in,
                              void* d_out, int out_size, void* d_ws, size_t ws_size,
                              hipStream_t stream) {
    const float* x = (const float*)d_in[0];
    float* out = (float*)d_out;
    const int H = 1024, W = 1024;
    const int B = in_sizes[0] / (H * W);
    dim3 grid(W / TSX, H / TSY, B);
    nlm_kernel<<<grid, dim3(512), 0, stream>>>(x, out, H, W);
}

// Round 13
// 862.588 us; speedup vs baseline: 1.1867x; 1.1867x over previous
//
#include <hip/hip_runtime.h>
#include <cstddef>

// NLM: h=7/255, template 7x7 (TH=3), search 21x21 (SH=10), reflect padding.
// Tile 32x32/block, 256 threads, software-pipelined disjoint wave roles,
// double-buffered vsh, ONE barrier per offset. Base = R9 (876us best).
// R14 = R9 + TRANSPOSED vsh (column-major, col stride 33 = odd):
//   DIAGNOSIS: R9's SQ_LDS_BANK_CONFLICT (1.086e8) is C's b64 vsh reads:
//   word addr py*42 + c8 + 2j is ALWAYS EVEN -> all 128 words/wave land on
//   the 16 even banks (2x serialization, 7x4 extra cy x 2 waves x 4096 x 441
//   = 1.01e8 ~= measured). Column-major vshT[col][row], stride 33 (odd):
//   C reads 14 scalars at banks (c8+m+py)%32 -> exactly 2/bank (free);
//   Bv writes 11 consecutive words at banks (cc+11g+k)%32 -> ~2/bank (free).
//   Same arithmetic sequence (bit-identical); LDS 25.6 -> 24.4 KB.
// R9 exact exp-block skip kept (exp2 underflow -> +0.0 for h > 3.84).
// Lessons: no ox-loop unrolling (R2); 114-lane scalar Bv (R5/R6); float vsh
// (R7); no LDS ring (R8); no parity swap (R10); no reg prefetch (R11); no
// offset-pair packing (R12); 32x32 tile, 256 thr (R13).

constexpr int TS    = 32;
constexpr int XSTR  = 61;            // odd -> benign bank aliasing
constexpr int XROWS = 59;            // image rows gy0-13 .. gy0+45
constexpr int XSZ   = XROWS * XSTR;  // 3599
constexpr int VT    = 33;            // vshT column stride (rows 0..32; 32=junk)
constexpr int VCOLS = 38;
constexpr int VS_SZ = VCOLS * VT;    // 1254 words per buffer

__device__ __forceinline__ int refl(int i, int n) {
    i = (i < 0) ? -i : i;
    return (i >= n) ? (2 * n - 2 - i) : i;
}

template<bool FAST>
__device__ __forceinline__ void nlm_body(const float* __restrict__ img,
                                         float* __restrict__ out,
                                         int H, int W, int gx0, int gy0,
                                         float* __restrict__ xs,
                                         float* __restrict__ vsh, int tid)
{
    // ---- load xs (clip to [0,1], reflect indexing) ----
    for (int e = tid; e < XSZ; e += 256) {
        int i = e / XSTR, j = e - i * XSTR;
        int jj = (j > 57) ? 57 : j;  // cols 58..60: stride pad (never read)
        int gy = refl(gy0 - 13 + i, H);
        int gx = refl(gx0 - 13 + jj, W);
        float v = img[(size_t)gy * W + gx];
        xs[e] = fminf(fmaxf(v, 0.0f), 1.0f);
    }
    __syncthreads();

    // ---- Bv setup: 114 lanes = 38 cols x 3 row-groups (11 rows, 17 q's) ----
    const bool bv = (tid < 114);
    float u[17];
    int   aB = 0;                    // FAST: single address, +i*XSTR rows
    int   aS[17];                    // EDGE: per-row reflected addresses
    int   wb = 0;
    {
        int t  = bv ? tid : 0;
        int g  = t / 38;
        int cc = t - g * 38;
        int r  = g * 11;
        int mxm10 = refl(gx0 + cc - 3, W) - gx0 + 3;
        if constexpr (FAST) {
            aB = r * XSTR + mxm10;
#pragma unroll
            for (int i = 0; i < 17; ++i)
                u[i] = xs[(r + i + 10) * XSTR + mxm10 + 10];
        } else {
#pragma unroll
            for (int i = 0; i < 17; ++i) {
                int my = refl(gy0 + r + i - 3, H) - gy0 + 13;
                u[i]  = xs[my * XSTR + mxm10 + 10];
                aS[i] = (my - 10) * XSTR + mxm10;
            }
        }
        wb = cc * VT + r;            // TRANSPOSED: column cc, rows r..r+10
    }

    // ---- C setup: 128 lanes = 32 rows x 4 groups of 8 cols ----
    const bool cact = (tid >= 128);
    const int ct = cact ? (tid - 128) : 0;
    const int py = ct >> 2;
    const int c8 = (ct & 3) * 8;
    const int vb = c8 * VT + py;                // TRANSPOSED read base
    int svC = (py + 3) * XSTR + (c8 + 3);       // row base, advances per oy

    int oxB = 0;                                 // uniform ox state machines
    int oxC = 0;

    float ws[8], ac[8];
#pragma unroll
    for (int k = 0; k < 8; ++k) { ws[k] = 0.f; ac[k] = 0.f; }
    // w = exp(-mean49(d)/H2) = exp2(K * sum49(d))
    const float K = -(65025.0f / 2401.0f) * 1.4426950408889634f;  // ~ -39.07
    const float HSKIP = 3.95f;  // h > 3.95 => h*K <= -154 => exp2 == +0.0f

    auto bv_step = [&](int buf) {
        if (bv) {
            float* vo = vsh + buf * VS_SZ + wb;
            float q[17];
            if constexpr (FAST) {
#pragma unroll
                for (int i = 0; i < 17; ++i)
                    q[i] = xs[aB + i * XSTR];
            } else {
#pragma unroll
                for (int i = 0; i < 17; ++i)
                    q[i] = xs[aS[i]];
            }
#pragma unroll
            for (int i = 0; i < 17; ++i) {
                float d = u[i] - q[i];
                q[i] = d * d;
            }
            float s[11];
            s[0] = ((q[0] + q[1]) + (q[2] + q[3])) + ((q[4] + q[5]) + q[6]);
#pragma unroll
            for (int k = 1; k < 11; ++k)
                s[k] = s[k - 1] + (q[k + 6] - q[k - 1]);
#pragma unroll
            for (int k = 0; k < 11; ++k)
                vo[k] = s[k];        // consecutive rows; row 32 junk (g=2)
            if constexpr (FAST) {
                aB += (oxB == 20) ? (XSTR - 20) : 1;
            } else {
                int step = (oxB == 20) ? (XSTR - 20) : 1;
#pragma unroll
                for (int i = 0; i < 17; ++i) aS[i] += step;
            }
        }
        oxB = (oxB == 20) ? 0 : (oxB + 1);
    };

    auto c_step = [&](int buf) {
        if (cact) {
            const float* vp = vsh + buf * VS_SZ + vb;
            float v0  = vp[0],       v1  = vp[VT],      v2  = vp[2 * VT];
            float v3  = vp[3 * VT],  v4  = vp[4 * VT],  v5  = vp[5 * VT];
            float v6  = vp[6 * VT],  v7  = vp[7 * VT],  v8  = vp[8 * VT];
            float v9  = vp[9 * VT],  v10 = vp[10 * VT], v11 = vp[11 * VT];
            float v12 = vp[12 * VT], v13 = vp[13 * VT];
            float h0 = ((v0 + v1) + (v2 + v3)) + ((v4 + v5) + v6);
            float h1 = h0 - v0 + v7;
            float h2 = h1 - v1 + v8;
            float h3 = h2 - v2 + v9;
            float h4 = h3 - v3 + v10;
            float h5 = h4 - v4 + v11;
            float h6 = h5 - v5 + v12;
            float h7 = h6 - v6 + v13;
            float m = fminf(fminf(fminf(h0, h1), fminf(h2, h3)),
                            fminf(fminf(h4, h5), fminf(h6, h7)));
            if (__builtin_expect(__ballot(m <= HSKIP) != 0ull, 0)) {
                const int sp = svC + oxC;
                float x0 = xs[sp],     x1 = xs[sp + 1];
                float x2 = xs[sp + 2], x3 = xs[sp + 3];
                float x4 = xs[sp + 4], x5 = xs[sp + 5];
                float x6 = xs[sp + 6], x7 = xs[sp + 7];
                float w;
                w = __builtin_amdgcn_exp2f(h0 * K); ws[0] += w; ac[0] = fmaf(w, x0, ac[0]);
                w = __builtin_amdgcn_exp2f(h1 * K); ws[1] += w; ac[1] = fmaf(w, x1, ac[1]);
                w = __builtin_amdgcn_exp2f(h2 * K); ws[2] += w; ac[2] = fmaf(w, x2, ac[2]);
                w = __builtin_amdgcn_exp2f(h3 * K); ws[3] += w; ac[3] = fmaf(w, x3, ac[3]);
                w = __builtin_amdgcn_exp2f(h4 * K); ws[4] += w; ac[4] = fmaf(w, x4, ac[4]);
                w = __builtin_amdgcn_exp2f(h5 * K); ws[5] += w; ac[5] = fmaf(w, x5, ac[5]);
                w = __builtin_amdgcn_exp2f(h6 * K); ws[6] += w; ac[6] = fmaf(w, x6, ac[6]);
                w = __builtin_amdgcn_exp2f(h7 * K); ws[7] += w; ac[7] = fmaf(w, x7, ac[7]);
            }
            // else: all 8 weights are exactly +0.0f for every lane -> no-op.
        }
        if (oxC == 20) { oxC = 0; svC += XSTR; } else { ++oxC; }
    };

    // ---- pipelined offset loop: Bv(i) || C(i-1), 1 barrier/iter ----
    bv_step(0);
    __syncthreads();
#pragma unroll 1
    for (int i = 1; i < 441; ++i) {
        bv_step(i & 1);
        c_step(1 - (i & 1));
        __syncthreads();
        // barrier fences: C's reads of buf (i-1)&1 from next iter's Bv writes
        // to that buffer, and Bv's writes of buf i&1 from next iter's C reads.
    }
    c_step(0);   // offset 440 lives in buffer 0

    if (cact) {
        float4 oA, oB;
        oA.x = fminf(fmaxf(ac[0] * __builtin_amdgcn_rcpf(ws[0]), 0.f), 1.f);
        oA.y = fminf(fmaxf(ac[1] * __builtin_amdgcn_rcpf(ws[1]), 0.f), 1.f);
        oA.z = fminf(fmaxf(ac[2] * __builtin_amdgcn_rcpf(ws[2]), 0.f), 1.f);
        oA.w = fminf(fmaxf(ac[3] * __builtin_amdgcn_rcpf(ws[3]), 0.f), 1.f);
        oB.x = fminf(fmaxf(ac[4] * __builtin_amdgcn_rcpf(ws[4]), 0.f), 1.f);
        oB.y = fminf(fmaxf(ac[5] * __builtin_amdgcn_rcpf(ws[5]), 0.f), 1.f);
        oB.z = fminf(fmaxf(ac[6] * __builtin_amdgcn_rcpf(ws[6]), 0.f), 1.f);
        oB.w = fminf(fmaxf(ac[7] * __builtin_amdgcn_rcpf(ws[7]), 0.f), 1.f);
        float* op = &out[((size_t)blockIdx.z * H + (gy0 + py)) * W + (gx0 + c8)];
        *reinterpret_cast<float4*>(op)     = oA;
        *reinterpret_cast<float4*>(op + 4) = oB;
    }
}

__global__ __launch_bounds__(256)
void nlm_kernel(const float* __restrict__ img_all, float* __restrict__ out,
                int H, int W) {
    __shared__ __align__(16) float xs[XSZ];
    __shared__ __align__(16) float vsh[2 * VS_SZ];
    const int tid = threadIdx.x;
    const int gx0 = blockIdx.x * TS;
    const int gy0 = blockIdx.y * TS;
    const float* img = img_all + (size_t)blockIdx.z * H * W;
    // FAST iff no patch-center row (gy0-3..gy0+35) folds at a y-edge.
    if (gy0 - 3 >= 0 && gy0 + 35 < H)
        nlm_body<true>(img, out, H, W, gx0, gy0, xs, vsh, tid);
    else
        nlm_body<false>(img, out, H, W, gx0, gy0, xs, vsh, tid);
}

extern "C" void kernel_launch(void* const* d_in, const int* in_sizes, int n_in,
                              void* d_out, int out_size, void* d_ws, size_t ws_size,
                              hipStream_t stream) {
    const float* x = (const float*)d_in[0];
    float* out = (float*)d_out;
    const int H = 1024, W = 1024;
    const int B = in_sizes[0] / (H * W);
    dim3 grid(W / TS, H / TS, B);
    nlm_kernel<<<grid, dim3(256), 0, stream>>>(x, out, H, W);
}